// Round 8
// baseline (345.535 us; speedup 1.0000x reference)
//
#include <hip/hip_runtime.h>

#define BIG_NEG_F (-4294967296.0f)

__device__ __forceinline__ float wave_sum(float v) {
#pragma unroll
    for (int m = 32; m; m >>= 1) v += __shfl_xor(v, m, 64);
    return v;
}
__device__ __forceinline__ float wave_max(float v) {
#pragma unroll
    for (int m = 32; m; m >>= 1) v = fmaxf(v, __shfl_xor(v, m, 64));
    return v;
}

// Fused: detect mask layout (u8/i32/i64) from first 2048 bytes, normalize this row's bit,
// x = seq*keep, q = ln1(x). One block per row.
__global__ __launch_bounds__(256) void prep_ln_kernel(const float* __restrict__ seq,
                                                      const unsigned char* __restrict__ mraw,
                                                      unsigned char* __restrict__ mout,
                                                      float* __restrict__ X, float* __restrict__ Q,
                                                      const float* __restrict__ g,
                                                      const float* __restrict__ be) {
    __shared__ int flags[2];
    __shared__ float ws[8];
    int row = blockIdx.x, tid = threadIdx.x;
    if (tid == 0) { flags[0] = 0; flags[1] = 0; }
    __syncthreads();
    for (int i = tid; i < 2048; i += 256) {
        if (mraw[i]) {
            if (i & 3) atomicOr(&flags[0], 1);
            else if (i & 4) atomicOr(&flags[1], 1);
        }
    }
    __syncthreads();
    int mode = flags[0] ? 0 : (flags[1] ? 1 : 2);  // 0=u8, 1=i32, 2=i64
    unsigned char mrow = (mode == 0) ? mraw[row] : (mode == 1) ? mraw[row * 4] : mraw[row * 8];
    if (tid == 0) mout[row] = mrow ? 1 : 0;
    int idx = row * 256 + tid;
    int w = tid >> 6, lane = tid & 63;
    float v = mrow ? 0.f : seq[idx];
    X[idx] = v;
    float s = wave_sum(v);
    if (lane == 0) ws[w] = s;
    __syncthreads();
    float mean = (ws[0] + ws[1] + ws[2] + ws[3]) * (1.f / 256.f);
    float d = v - mean;
    float s2 = wave_sum(d * d);
    if (lane == 0) ws[4 + w] = s2;
    __syncthreads();
    float var = (ws[4] + ws[5] + ws[6] + ws[7]) * (1.f / 256.f);
    Q[idx] = d / sqrtf(var + 1e-8f) * g[tid] + be[tid];
}

// row layernorm over H=256, one block per row; shfl reductions (2 barriers)
__global__ __launch_bounds__(256) void ln_kernel(const float* __restrict__ X, float* __restrict__ Y,
                                                 const float* __restrict__ g,
                                                 const float* __restrict__ be) {
    __shared__ float ws[8];
    int row = blockIdx.x, tid = threadIdx.x;
    int idx = row * 256 + tid;
    int w = tid >> 6, lane = tid & 63;
    float v = X[idx];
    float s = wave_sum(v);
    if (lane == 0) ws[w] = s;
    __syncthreads();
    float mean = (ws[0] + ws[1] + ws[2] + ws[3]) * (1.f / 256.f);
    float d = v - mean;
    float s2 = wave_sum(d * d);
    if (lane == 0) ws[4 + w] = s2;
    __syncthreads();
    float var = (ws[4] + ws[5] + ws[6] + ws[7]) * (1.f / 256.f);
    Y[idx] = d / sqrtf(var + 1e-8f) * g[tid] + be[tid];
}

struct GemmJob {
    const float* A;     // [2048,256]
    const float* W;     // [256,256] row-major (out,in)
    const float* bias;  // [256]
    const float* pos;   // [256,256] per-position add, or null
    float* C;           // [2048,256]
};

// 64x64 tile, 4x4/thread (1 B LDS per FLOP — 32x32's 2 B/FLOP regressed 21 µs, round 7),
// BK=32, double-buffered LDS: one barrier per K-step (9 total vs 16). Global prefetch
// retires under the 32-iter compute; LDS write of the next tile follows compute.
__global__ __launch_bounds__(256) void gemm64_kernel(GemmJob j0, GemmJob j1, GemmJob j2) {
    GemmJob J = (blockIdx.z == 0) ? j0 : (blockIdx.z == 1 ? j1 : j2);
    __shared__ float AsT[2][32][68];
    __shared__ float WsT[2][32][68];
    int tid = threadIdx.x;
    int n0 = blockIdx.x * 64, m0 = blockIdx.y * 64;
    int r = tid >> 4, c = tid & 15;
    int li = tid >> 2, lk = (tid & 3) * 8;
    const float* Ab = J.A + (m0 + li) * 256 + lk;
    const float* Wb = J.W + (n0 + li) * 256 + lk;
    float4 a0 = *(const float4*)(Ab);
    float4 a1 = *(const float4*)(Ab + 4);
    float4 w0 = *(const float4*)(Wb);
    float4 w1 = *(const float4*)(Wb + 4);
    AsT[0][lk + 0][li] = a0.x; AsT[0][lk + 1][li] = a0.y; AsT[0][lk + 2][li] = a0.z; AsT[0][lk + 3][li] = a0.w;
    AsT[0][lk + 4][li] = a1.x; AsT[0][lk + 5][li] = a1.y; AsT[0][lk + 6][li] = a1.z; AsT[0][lk + 7][li] = a1.w;
    WsT[0][lk + 0][li] = w0.x; WsT[0][lk + 1][li] = w0.y; WsT[0][lk + 2][li] = w0.z; WsT[0][lk + 3][li] = w0.w;
    WsT[0][lk + 4][li] = w1.x; WsT[0][lk + 5][li] = w1.y; WsT[0][lk + 6][li] = w1.z; WsT[0][lk + 7][li] = w1.w;
    __syncthreads();
    float acc[4][4] = {};
#pragma unroll 2
    for (int step = 0; step < 8; ++step) {
        int cur = step & 1;
        if (step < 7) {
            a0 = *(const float4*)(Ab + (step + 1) * 32);
            a1 = *(const float4*)(Ab + (step + 1) * 32 + 4);
            w0 = *(const float4*)(Wb + (step + 1) * 32);
            w1 = *(const float4*)(Wb + (step + 1) * 32 + 4);
        }
#pragma unroll
        for (int kk = 0; kk < 32; ++kk) {
            float4 a = *(const float4*)&AsT[cur][kk][r * 4];
            float4 bv = *(const float4*)&WsT[cur][kk][c * 4];
            acc[0][0] += a.x * bv.x; acc[0][1] += a.x * bv.y; acc[0][2] += a.x * bv.z; acc[0][3] += a.x * bv.w;
            acc[1][0] += a.y * bv.x; acc[1][1] += a.y * bv.y; acc[1][2] += a.y * bv.z; acc[1][3] += a.y * bv.w;
            acc[2][0] += a.z * bv.x; acc[2][1] += a.z * bv.y; acc[2][2] += a.z * bv.z; acc[2][3] += a.z * bv.w;
            acc[3][0] += a.w * bv.x; acc[3][1] += a.w * bv.y; acc[3][2] += a.w * bv.z; acc[3][3] += a.w * bv.w;
        }
        if (step < 7) {
            int nx = cur ^ 1;
            AsT[nx][lk + 0][li] = a0.x; AsT[nx][lk + 1][li] = a0.y; AsT[nx][lk + 2][li] = a0.z; AsT[nx][lk + 3][li] = a0.w;
            AsT[nx][lk + 4][li] = a1.x; AsT[nx][lk + 5][li] = a1.y; AsT[nx][lk + 6][li] = a1.z; AsT[nx][lk + 7][li] = a1.w;
            WsT[nx][lk + 0][li] = w0.x; WsT[nx][lk + 1][li] = w0.y; WsT[nx][lk + 2][li] = w0.z; WsT[nx][lk + 3][li] = w0.w;
            WsT[nx][lk + 4][li] = w1.x; WsT[nx][lk + 5][li] = w1.y; WsT[nx][lk + 6][li] = w1.z; WsT[nx][lk + 7][li] = w1.w;
        }
        __syncthreads();
    }
    int n = n0 + c * 4;
    float4 b4 = *(const float4*)(J.bias + n);
#pragma unroll
    for (int i = 0; i < 4; ++i) {
        int m = m0 + r * 4 + i;
        float4 v;
        v.x = acc[i][0] + b4.x; v.y = acc[i][1] + b4.y;
        v.z = acc[i][2] + b4.z; v.w = acc[i][3] + b4.w;
        if (J.pos) {
            float4 p4 = *(const float4*)(J.pos + (m & 255) * 256 + n);
            v.x += p4.x; v.y += p4.y; v.z += p4.z; v.w += p4.w;
        }
        *(float4*)(J.C + m * 256 + n) = v;
    }
}

// 32x32 tile, 2x2/thread, BK=32 — FFN GEMMs (512 blocks). relu / res / mask epilogue.
// Double-buffered LDS, one barrier per K-step.
__global__ __launch_bounds__(256) void gemm32_kernel(const float* __restrict__ A,
                                                     const float* __restrict__ W,
                                                     const float* __restrict__ bias,
                                                     const float* __restrict__ res,
                                                     const unsigned char* __restrict__ maskm,
                                                     float* __restrict__ C, int relu) {
    __shared__ float AsT[2][32][34];
    __shared__ float WsT[2][32][34];
    int tid = threadIdx.x;
    int n0 = blockIdx.x * 32, m0 = blockIdx.y * 32;
    int r = tid >> 4, c = tid & 15;
    int li = tid >> 3, lk = (tid & 7) * 4;
    const float* Ab = A + (m0 + li) * 256 + lk;
    const float* Wb = W + (n0 + li) * 256 + lk;
    float4 av = *(const float4*)(Ab);
    float4 wv = *(const float4*)(Wb);
    AsT[0][lk + 0][li] = av.x; AsT[0][lk + 1][li] = av.y; AsT[0][lk + 2][li] = av.z; AsT[0][lk + 3][li] = av.w;
    WsT[0][lk + 0][li] = wv.x; WsT[0][lk + 1][li] = wv.y; WsT[0][lk + 2][li] = wv.z; WsT[0][lk + 3][li] = wv.w;
    __syncthreads();
    float acc00 = 0, acc01 = 0, acc10 = 0, acc11 = 0;
#pragma unroll 2
    for (int step = 0; step < 8; ++step) {
        int cur = step & 1;
        if (step < 7) {
            av = *(const float4*)(Ab + (step + 1) * 32);
            wv = *(const float4*)(Wb + (step + 1) * 32);
        }
#pragma unroll
        for (int kk = 0; kk < 32; ++kk) {
            float2 a = *(const float2*)&AsT[cur][kk][r * 2];
            float2 b = *(const float2*)&WsT[cur][kk][c * 2];
            acc00 += a.x * b.x; acc01 += a.x * b.y;
            acc10 += a.y * b.x; acc11 += a.y * b.y;
        }
        if (step < 7) {
            int nx = cur ^ 1;
            AsT[nx][lk + 0][li] = av.x; AsT[nx][lk + 1][li] = av.y; AsT[nx][lk + 2][li] = av.z; AsT[nx][lk + 3][li] = av.w;
            WsT[nx][lk + 0][li] = wv.x; WsT[nx][lk + 1][li] = wv.y; WsT[nx][lk + 2][li] = wv.z; WsT[nx][lk + 3][li] = wv.w;
        }
        __syncthreads();
    }
    float accs[2][2] = {{acc00, acc01}, {acc10, acc11}};
#pragma unroll
    for (int i = 0; i < 2; ++i) {
        int m = m0 + r * 2 + i;
#pragma unroll
        for (int jj = 0; jj < 2; ++jj) {
            int n = n0 + c * 2 + jj;
            float v = accs[i][jj] + bias[n];
            if (relu) v = fmaxf(v, 0.f);
            if (res) v += res[m * 256 + n];
            if (maskm && maskm[m]) v = 0.f;
            C[m * 256 + n] = v;
        }
    }
}

// 2048 one-qpos blocks. b = bid&7 keeps XCD affinity (each XCD touches one batch's
// K/V/Q/qres/tm ~2.3MB -> fits 4MiB private L2; FETCH 51->9.3MB measured). qpos map is
// per-CU balanced: i=bid>>3, j=i&31, a=i>>5, q0=j*4+(a>>1), qpos=(a&1)?q0:255-q0 —
// bijective over [0,256); under round-robin (id%8->XCD, (id/8)%32->CU) each CU's 8
// blocks sum to exactly 1028 rows. Inner loops batch-2 (4 float4 in flight): fits the
// 64-VGPR budget of __launch_bounds__(256,8) with NO scratch traffic. Batch-4 spills —
// verified rounds 1/2/4/6 (WRITE_SIZE 7.9-22.5MB vs 2.0MB here). Do not raise depth.
__global__ __launch_bounds__(256, 8) void attn_kernel(
    const float* __restrict__ Q, const float* __restrict__ Kp, const float* __restrict__ Vp,
    const float* __restrict__ qres, const int* __restrict__ tm,
    const float* __restrict__ tK, const float* __restrict__ tV,
    const float* __restrict__ g2, const float* __restrict__ b2,
    float* __restrict__ X2) {
    int bid = (int)blockIdx.x;
    int b = bid & 7;                    // XCD-aligned batch
    int i6 = bid >> 3;                  // 0..255
    int jj6 = i6 & 31, a6 = i6 >> 5;
    int q0m = jj6 * 4 + (a6 >> 1);      // 0..127
    int qpos = (a6 & 1) ? q0m : 255 - q0m;
    int tid = threadIdx.x, w = tid >> 6, lane = tid & 63;
    __shared__ float qrow[256];
    __shared__ int   stm[256];
    __shared__ float p[4][264];     // 264: writer lanes spread banks
    __shared__ float opart[4][256];
    __shared__ float denom[4];
    __shared__ float lnws[8];

    int rowbase = (b * 256 + qpos) * 256;
    qrow[tid] = Q[rowbase + tid];
    {
        int t = tm[rowbase + tid];
        stm[tid] = t < 0 ? 0 : (t > 512 ? 512 : t);
    }
    __syncthreads();

    // --- phase 1: scores, k ≡ w (mod 4) per wave — balanced across waves; batch-2
    {
        int h = lane >> 4;
        const float* qr = qrow + lane * 4;
        float q0 = qr[0], q1 = qr[1], q2 = qr[2], q3 = qr[3];
        const float* Kb  = Kp + (size_t)(b << 8) * 256 + lane * 4;
        const float* tKb = tK + lane * 4;
        int nact = (qpos >= w) ? ((qpos - w) >> 2) + 1 : 0;  // #k in {w, w+4, ...} <= qpos
        int i = 0;
        for (; i + 2 <= nact; i += 2) {
            int k0 = w + 4 * i;          // rows k0, k0+4
            float4 kv0 = *(const float4*)(Kb + (k0    ) * 256);
            float4 kv1 = *(const float4*)(Kb + (k0 + 4) * 256);
            float4 t0 = *(const float4*)(tKb + stm[k0    ] * 256);
            float4 t1 = *(const float4*)(tKb + stm[k0 + 4] * 256);
            float s0 = q0 * (kv0.x + t0.x) + q1 * (kv0.y + t0.y) + q2 * (kv0.z + t0.z) + q3 * (kv0.w + t0.w);
            float s1 = q0 * (kv1.x + t1.x) + q1 * (kv1.y + t1.y) + q2 * (kv1.z + t1.z) + q3 * (kv1.w + t1.w);
            s0 += __shfl_xor(s0, 1, 64); s1 += __shfl_xor(s1, 1, 64);
            s0 += __shfl_xor(s0, 2, 64); s1 += __shfl_xor(s1, 2, 64);
            s0 += __shfl_xor(s0, 4, 64); s1 += __shfl_xor(s1, 4, 64);
            s0 += __shfl_xor(s0, 8, 64); s1 += __shfl_xor(s1, 8, 64);
            if ((lane & 15) == 0) {
                p[h][k0    ] = s0 * 0.125f;
                p[h][k0 + 4] = s1 * 0.125f;
            }
        }
        if (i < nact) {
            int k = w + 4 * i;
            float4 kv = *(const float4*)(Kb + k * 256);
            float4 t4 = *(const float4*)(tKb + stm[k] * 256);
            float s = q0 * (kv.x + t4.x) + q1 * (kv.y + t4.y) + q2 * (kv.z + t4.z) + q3 * (kv.w + t4.w);
            s += __shfl_xor(s, 1, 64);
            s += __shfl_xor(s, 2, 64);
            s += __shfl_xor(s, 4, 64);
            s += __shfl_xor(s, 8, 64);
            if ((lane & 15) == 0) p[h][k] = s * 0.125f;
        }
    }
    __syncthreads();

    // --- softmax: wave w owns head w; invalid k (> qpos) masked at read (p holds garbage there)
    {
        float* ph = &p[w][0];
        float v0 = (lane       <= qpos) ? ph[lane      ] : BIG_NEG_F;
        float v1 = (lane + 64  <= qpos) ? ph[lane + 64 ] : BIG_NEG_F;
        float v2 = (lane + 128 <= qpos) ? ph[lane + 128] : BIG_NEG_F;
        float v3 = (lane + 192 <= qpos) ? ph[lane + 192] : BIG_NEG_F;
        float mx = wave_max(fmaxf(fmaxf(v0, v1), fmaxf(v2, v3)));
        float e0 = __expf(v0 - mx), e1 = __expf(v1 - mx), e2 = __expf(v2 - mx), e3 = __expf(v3 - mx);
        ph[lane] = e0; ph[lane + 64] = e1; ph[lane + 128] = e2; ph[lane + 192] = e3;
        float ssum = wave_sum(e0 + e1 + e2 + e3);
        if (lane == 0) denom[w] = ssum;
    }
    __syncthreads();

    // --- phase 3: PV, batch-2 with independent accumulators
    {
        int hh = lane >> 4;                 // head of this lane's 4 dims
        const float* Vb  = Vp + (size_t)(b << 8) * 256 + lane * 4;
        const float* tVb = tV + lane * 4;
        const float* prow = &p[hh][0];
        float4 a0 = {0.f, 0.f, 0.f, 0.f}, a1 = a0;
        int cnt = (qpos >= w) ? ((qpos - w) >> 2) + 1 : 0;
        int i = 0;
        for (; i + 2 <= cnt; i += 2) {
            int k0 = w + 4 * i;
            float p0 = prow[k0], p1 = prow[k0 + 4];
            float4 v0 = *(const float4*)(Vb + (k0    ) * 256);
            float4 v1 = *(const float4*)(Vb + (k0 + 4) * 256);
            float4 u0 = *(const float4*)(tVb + stm[k0    ] * 256);
            float4 u1 = *(const float4*)(tVb + stm[k0 + 4] * 256);
            a0.x += p0 * (v0.x + u0.x); a0.y += p0 * (v0.y + u0.y); a0.z += p0 * (v0.z + u0.z); a0.w += p0 * (v0.w + u0.w);
            a1.x += p1 * (v1.x + u1.x); a1.y += p1 * (v1.y + u1.y); a1.z += p1 * (v1.z + u1.z); a1.w += p1 * (v1.w + u1.w);
        }
        if (i < cnt) {
            int k2 = w + 4 * i;
            float pk = prow[k2];
            float4 v = *(const float4*)(Vb + k2 * 256);
            float4 t = *(const float4*)(tVb + stm[k2] * 256);
            a0.x += pk * (v.x + t.x);
            a0.y += pk * (v.y + t.y);
            a0.z += pk * (v.z + t.z);
            a0.w += pk * (v.w + t.w);
        }
        float4 o;
        o.x = a0.x + a1.x;
        o.y = a0.y + a1.y;
        o.z = a0.z + a1.z;
        o.w = a0.w + a1.w;
        *(float4*)&opart[w][lane * 4] = o;
    }
    __syncthreads();

    // --- combine + fused ln2
    {
        int d = tid, h = tid >> 6;
        float tot = opart[0][d] + opart[1][d] + opart[2][d] + opart[3][d];
        float xv = qres[rowbase + d] + tot / denom[h];
        float s = wave_sum(xv);
        if (lane == 0) lnws[w] = s;
        __syncthreads();
        float mean = (lnws[0] + lnws[1] + lnws[2] + lnws[3]) * (1.f / 256.f);
        float dd = xv - mean;
        float s2 = wave_sum(dd * dd);
        if (lane == 0) lnws[4 + w] = s2;
        __syncthreads();
        float var = (lnws[4] + lnws[5] + lnws[6] + lnws[7]) * (1.f / 256.f);
        X2[rowbase + d] = dd / sqrtf(var + 1e-8f) * g2[d] + b2[d];
    }
}

extern "C" void kernel_launch(void* const* d_in, const int* in_sizes, int n_in,
                              void* d_out, int out_size, void* d_ws, size_t ws_size,
                              hipStream_t stream) {
    const unsigned char* mask_raw = (const unsigned char*)d_in[0];
    const float* seq  = (const float*)d_in[1];
    const int*   tm   = (const int*)d_in[3];
    const float* Wq   = (const float*)d_in[5];
    const float* bq   = (const float*)d_in[6];
    const float* Wk   = (const float*)d_in[7];
    const float* bk   = (const float*)d_in[8];
    const float* Wv   = (const float*)d_in[9];
    const float* bv   = (const float*)d_in[10];
    const float* ln1g = (const float*)d_in[11];
    const float* ln1b = (const float*)d_in[12];
    const float* ln2g = (const float*)d_in[13];
    const float* ln2b = (const float*)d_in[14];
    const float* W1   = (const float*)d_in[15];
    const float* b1   = (const float*)d_in[16];
    const float* W2   = (const float*)d_in[17];
    const float* b2   = (const float*)d_in[18];
    const float* posK = (const float*)d_in[19];
    const float* posV = (const float*)d_in[20];
    const float* tK   = (const float*)d_in[21];
    const float* tV   = (const float*)d_in[22];
    const float* lnfg = (const float*)d_in[23];
    const float* lnfb = (const float*)d_in[24];

    const int NEL = 8 * 256 * 256;
    float* x   = (float*)d_ws;
    float* q   = x   + NEL;
    float* Qb  = q   + NEL;
    float* KpB = Qb  + NEL;
    float* VpB = KpB + NEL;
    float* x2  = VpB + NEL;
    float* hb  = x2  + NEL;
    unsigned char* mask = (unsigned char*)(hb + NEL);

    dim3 gQKV(4, 32, 3);
    dim3 gFFN(8, 64);

    prep_ln_kernel<<<2048, 256, 0, stream>>>(seq, mask_raw, mask, x, q, ln1g, ln1b);
    for (int blk = 0; blk < 2; ++blk) {
        int o1 = blk * 256, oW = blk * 256 * 256;
        GemmJob jq = {q, Wq + oW, bq + o1, nullptr, Qb};
        GemmJob jk = {x, Wk + oW, bk + o1, posK,    KpB};
        GemmJob jv = {x, Wv + oW, bv + o1, posV,    VpB};
        gemm64_kernel<<<gQKV, 256, 0, stream>>>(jq, jk, jv);
        attn_kernel<<<2048, 256, 0, stream>>>(Qb, KpB, VpB, q, tm, tK, tV,
                                              ln2g + o1, ln2b + o1, x2);
        gemm32_kernel<<<gFFN, 256, 0, stream>>>(x2, W1 + oW, b1 + o1, nullptr, nullptr, hb, 1);
        gemm32_kernel<<<gFFN, 256, 0, stream>>>(hb, W2 + oW, b2 + o1, x2, mask, x, 0);
        if (blk == 0) ln_kernel<<<2048, 256, 0, stream>>>(x, q, ln1g + 256, ln1b + 256);
    }
    ln_kernel<<<2048, 256, 0, stream>>>(x, (float*)d_out, lnfg, lnfb);
}

// Round 9
// 272.154 us; speedup vs baseline: 1.2696x; 1.2696x over previous
//
#include <hip/hip_runtime.h>

#define BIG_NEG_F (-4294967296.0f)

__device__ __forceinline__ float wave_sum(float v) {
#pragma unroll
    for (int m = 32; m; m >>= 1) v += __shfl_xor(v, m, 64);
    return v;
}
__device__ __forceinline__ float wave_max(float v) {
#pragma unroll
    for (int m = 32; m; m >>= 1) v = fmaxf(v, __shfl_xor(v, m, 64));
    return v;
}

// Fused: detect mask layout (u8/i32/i64) from first 2048 bytes, normalize this row's bit,
// x = seq*keep, q = ln1(x). One block per row.
__global__ __launch_bounds__(256) void prep_ln_kernel(const float* __restrict__ seq,
                                                      const unsigned char* __restrict__ mraw,
                                                      unsigned char* __restrict__ mout,
                                                      float* __restrict__ X, float* __restrict__ Q,
                                                      const float* __restrict__ g,
                                                      const float* __restrict__ be) {
    __shared__ int flags[2];
    __shared__ float ws[8];
    int row = blockIdx.x, tid = threadIdx.x;
    if (tid == 0) { flags[0] = 0; flags[1] = 0; }
    __syncthreads();
    for (int i = tid; i < 2048; i += 256) {
        if (mraw[i]) {
            if (i & 3) atomicOr(&flags[0], 1);
            else if (i & 4) atomicOr(&flags[1], 1);
        }
    }
    __syncthreads();
    int mode = flags[0] ? 0 : (flags[1] ? 1 : 2);  // 0=u8, 1=i32, 2=i64
    unsigned char mrow = (mode == 0) ? mraw[row] : (mode == 1) ? mraw[row * 4] : mraw[row * 8];
    if (tid == 0) mout[row] = mrow ? 1 : 0;
    int idx = row * 256 + tid;
    int w = tid >> 6, lane = tid & 63;
    float v = mrow ? 0.f : seq[idx];
    X[idx] = v;
    float s = wave_sum(v);
    if (lane == 0) ws[w] = s;
    __syncthreads();
    float mean = (ws[0] + ws[1] + ws[2] + ws[3]) * (1.f / 256.f);
    float d = v - mean;
    float s2 = wave_sum(d * d);
    if (lane == 0) ws[4 + w] = s2;
    __syncthreads();
    float var = (ws[4] + ws[5] + ws[6] + ws[7]) * (1.f / 256.f);
    Q[idx] = d / sqrtf(var + 1e-8f) * g[tid] + be[tid];
}

// row layernorm over H=256, one block per row; shfl reductions (2 barriers)
__global__ __launch_bounds__(256) void ln_kernel(const float* __restrict__ X, float* __restrict__ Y,
                                                 const float* __restrict__ g,
                                                 const float* __restrict__ be) {
    __shared__ float ws[8];
    int row = blockIdx.x, tid = threadIdx.x;
    int idx = row * 256 + tid;
    int w = tid >> 6, lane = tid & 63;
    float v = X[idx];
    float s = wave_sum(v);
    if (lane == 0) ws[w] = s;
    __syncthreads();
    float mean = (ws[0] + ws[1] + ws[2] + ws[3]) * (1.f / 256.f);
    float d = v - mean;
    float s2 = wave_sum(d * d);
    if (lane == 0) ws[4 + w] = s2;
    __syncthreads();
    float var = (ws[4] + ws[5] + ws[6] + ws[7]) * (1.f / 256.f);
    Y[idx] = d / sqrtf(var + 1e-8f) * g[tid] + be[tid];
}

struct GemmJob {
    const float* A;     // [2048,256]
    const float* W;     // [256,256] row-major (out,in)
    const float* bias;  // [256]
    const float* pos;   // [256,256] per-position add, or null
    float* C;           // [2048,256]
};

// 64x64 tile, 4x4/thread, BK=32, register-prefetch (single LDS buffer — dbuf blew VGPR
// to 256 / occupancy 7%, round 8). Store swizzle: transposed stores AsT[row][col] with
// row stride 68 put rows 8 apart on identical banks (8*68 ≡ 0 mod 32) -> 4-way conflict
// on every scalar store (1.18M conflicts/dispatch measured). Fix: rotate col by
// 16*(row>>3): col' = (li + 16*(tid&3)) & 63 — write banks (4j+li+16t) mod 32 = exactly
// 2-way = free. Reads use col' = (x*4 + 16*(kk>>3)) & 63, still float4-aligned;
// kk>>3 is compile-time under the unroll.
__global__ __launch_bounds__(256) void gemm64_kernel(GemmJob j0, GemmJob j1, GemmJob j2) {
    GemmJob J = (blockIdx.z == 0) ? j0 : (blockIdx.z == 1 ? j1 : j2);
    __shared__ float AsT[32][68];
    __shared__ float WsT[32][68];
    int tid = threadIdx.x;
    int n0 = blockIdx.x * 64, m0 = blockIdx.y * 64;
    int r = tid >> 4, c = tid & 15;
    int li = tid >> 2, lk = (tid & 3) * 8;
    int wcol = (li + ((tid & 3) << 4)) & 63;   // rows lk..lk+7 all have row>>3 == tid&3
    const float* Ab = J.A + (m0 + li) * 256 + lk;
    const float* Wb = J.W + (n0 + li) * 256 + lk;
    float4 a0 = *(const float4*)(Ab);
    float4 a1 = *(const float4*)(Ab + 4);
    float4 w0 = *(const float4*)(Wb);
    float4 w1 = *(const float4*)(Wb + 4);
    float acc[4][4] = {};
    for (int k0 = 0; k0 < 256; k0 += 32) {
        AsT[lk + 0][wcol] = a0.x; AsT[lk + 1][wcol] = a0.y; AsT[lk + 2][wcol] = a0.z; AsT[lk + 3][wcol] = a0.w;
        AsT[lk + 4][wcol] = a1.x; AsT[lk + 5][wcol] = a1.y; AsT[lk + 6][wcol] = a1.z; AsT[lk + 7][wcol] = a1.w;
        WsT[lk + 0][wcol] = w0.x; WsT[lk + 1][wcol] = w0.y; WsT[lk + 2][wcol] = w0.z; WsT[lk + 3][wcol] = w0.w;
        WsT[lk + 4][wcol] = w1.x; WsT[lk + 5][wcol] = w1.y; WsT[lk + 6][wcol] = w1.z; WsT[lk + 7][wcol] = w1.w;
        __syncthreads();
        if (k0 + 32 < 256) {
            a0 = *(const float4*)(Ab + k0 + 32);
            a1 = *(const float4*)(Ab + k0 + 36);
            w0 = *(const float4*)(Wb + k0 + 32);
            w1 = *(const float4*)(Wb + k0 + 36);
        }
#pragma unroll
        for (int kk = 0; kk < 32; ++kk) {
            int ca = ((r * 4) + ((kk >> 3) << 4)) & 63;
            int cb = ((c * 4) + ((kk >> 3) << 4)) & 63;
            float4 a = *(const float4*)&AsT[kk][ca];
            float4 bv = *(const float4*)&WsT[kk][cb];
            acc[0][0] += a.x * bv.x; acc[0][1] += a.x * bv.y; acc[0][2] += a.x * bv.z; acc[0][3] += a.x * bv.w;
            acc[1][0] += a.y * bv.x; acc[1][1] += a.y * bv.y; acc[1][2] += a.y * bv.z; acc[1][3] += a.y * bv.w;
            acc[2][0] += a.z * bv.x; acc[2][1] += a.z * bv.y; acc[2][2] += a.z * bv.z; acc[2][3] += a.z * bv.w;
            acc[3][0] += a.w * bv.x; acc[3][1] += a.w * bv.y; acc[3][2] += a.w * bv.z; acc[3][3] += a.w * bv.w;
        }
        __syncthreads();
    }
    int n = n0 + c * 4;
    float4 b4 = *(const float4*)(J.bias + n);
#pragma unroll
    for (int i = 0; i < 4; ++i) {
        int m = m0 + r * 4 + i;
        float4 v;
        v.x = acc[i][0] + b4.x; v.y = acc[i][1] + b4.y;
        v.z = acc[i][2] + b4.z; v.w = acc[i][3] + b4.w;
        if (J.pos) {
            float4 p4 = *(const float4*)(J.pos + (m & 255) * 256 + n);
            v.x += p4.x; v.y += p4.y; v.z += p4.z; v.w += p4.w;
        }
        *(float4*)(J.C + m * 256 + n) = v;
    }
}

// 32x32 tile, 2x2/thread, BK=32 — FFN GEMMs (512 blocks). relu / res / mask epilogue.
// Register-prefetch, single LDS buffer. Store banks here are (2lk+li+2j) mod 32 ≈ 2-way
// already (stride 34 ≡ 2 mod 32) — no swizzle needed.
__global__ __launch_bounds__(256) void gemm32_kernel(const float* __restrict__ A,
                                                     const float* __restrict__ W,
                                                     const float* __restrict__ bias,
                                                     const float* __restrict__ res,
                                                     const unsigned char* __restrict__ maskm,
                                                     float* __restrict__ C, int relu) {
    __shared__ float AsT[32][34];
    __shared__ float WsT[32][34];
    int tid = threadIdx.x;
    int n0 = blockIdx.x * 32, m0 = blockIdx.y * 32;
    int r = tid >> 4, c = tid & 15;
    int li = tid >> 3, lk = (tid & 7) * 4;
    const float* Ab = A + (m0 + li) * 256 + lk;
    const float* Wb = W + (n0 + li) * 256 + lk;
    float4 av = *(const float4*)(Ab);
    float4 wv = *(const float4*)(Wb);
    float acc00 = 0, acc01 = 0, acc10 = 0, acc11 = 0;
    for (int k0 = 0; k0 < 256; k0 += 32) {
        AsT[lk + 0][li] = av.x; AsT[lk + 1][li] = av.y; AsT[lk + 2][li] = av.z; AsT[lk + 3][li] = av.w;
        WsT[lk + 0][li] = wv.x; WsT[lk + 1][li] = wv.y; WsT[lk + 2][li] = wv.z; WsT[lk + 3][li] = wv.w;
        __syncthreads();
        if (k0 + 32 < 256) {
            av = *(const float4*)(Ab + k0 + 32);
            wv = *(const float4*)(Wb + k0 + 32);
        }
#pragma unroll
        for (int kk = 0; kk < 32; ++kk) {
            float2 a = *(const float2*)&AsT[kk][r * 2];
            float2 b = *(const float2*)&WsT[kk][c * 2];
            acc00 += a.x * b.x; acc01 += a.x * b.y;
            acc10 += a.y * b.x; acc11 += a.y * b.y;
        }
        __syncthreads();
    }
    float accs[2][2] = {{acc00, acc01}, {acc10, acc11}};
#pragma unroll
    for (int i = 0; i < 2; ++i) {
        int m = m0 + r * 2 + i;
#pragma unroll
        for (int jj = 0; jj < 2; ++jj) {
            int n = n0 + c * 2 + jj;
            float v = accs[i][jj] + bias[n];
            if (relu) v = fmaxf(v, 0.f);
            if (res) v += res[m * 256 + n];
            if (maskm && maskm[m]) v = 0.f;
            C[m * 256 + n] = v;
        }
    }
}

// 2048 one-qpos blocks. b = bid&7 keeps XCD affinity (each XCD touches one batch's
// K/V/Q/qres/tm ~2.3MB -> fits 4MiB private L2; FETCH 51->9.3MB measured). qpos map is
// per-CU balanced: i=bid>>3, j=i&31, a=i>>5, q0=j*4+(a>>1), qpos=(a&1)?q0:255-q0 —
// bijective over [0,256); under round-robin (id%8->XCD, (id/8)%32->CU) each CU's 8
// blocks sum to exactly 1028 rows. Inner loops batch-2 (4 float4 in flight): fits the
// 64-VGPR budget of __launch_bounds__(256,8) with NO scratch traffic. Batch-4 spills —
// verified rounds 1/2/4/6 (WRITE_SIZE 7.9-22.5MB vs 2.0MB here). Do not raise depth.
__global__ __launch_bounds__(256, 8) void attn_kernel(
    const float* __restrict__ Q, const float* __restrict__ Kp, const float* __restrict__ Vp,
    const float* __restrict__ qres, const int* __restrict__ tm,
    const float* __restrict__ tK, const float* __restrict__ tV,
    const float* __restrict__ g2, const float* __restrict__ b2,
    float* __restrict__ X2) {
    int bid = (int)blockIdx.x;
    int b = bid & 7;                    // XCD-aligned batch
    int i6 = bid >> 3;                  // 0..255
    int jj6 = i6 & 31, a6 = i6 >> 5;
    int q0m = jj6 * 4 + (a6 >> 1);      // 0..127
    int qpos = (a6 & 1) ? q0m : 255 - q0m;
    int tid = threadIdx.x, w = tid >> 6, lane = tid & 63;
    __shared__ float qrow[256];
    __shared__ int   stm[256];
    __shared__ float p[4][264];     // 264: writer lanes spread banks
    __shared__ float opart[4][256];
    __shared__ float denom[4];
    __shared__ float lnws[8];

    int rowbase = (b * 256 + qpos) * 256;
    qrow[tid] = Q[rowbase + tid];
    {
        int t = tm[rowbase + tid];
        stm[tid] = t < 0 ? 0 : (t > 512 ? 512 : t);
    }
    __syncthreads();

    // --- phase 1: scores, k ≡ w (mod 4) per wave — balanced across waves; batch-2
    {
        int h = lane >> 4;
        const float* qr = qrow + lane * 4;
        float q0 = qr[0], q1 = qr[1], q2 = qr[2], q3 = qr[3];
        const float* Kb  = Kp + (size_t)(b << 8) * 256 + lane * 4;
        const float* tKb = tK + lane * 4;
        int nact = (qpos >= w) ? ((qpos - w) >> 2) + 1 : 0;  // #k in {w, w+4, ...} <= qpos
        int i = 0;
        for (; i + 2 <= nact; i += 2) {
            int k0 = w + 4 * i;          // rows k0, k0+4
            float4 kv0 = *(const float4*)(Kb + (k0    ) * 256);
            float4 kv1 = *(const float4*)(Kb + (k0 + 4) * 256);
            float4 t0 = *(const float4*)(tKb + stm[k0    ] * 256);
            float4 t1 = *(const float4*)(tKb + stm[k0 + 4] * 256);
            float s0 = q0 * (kv0.x + t0.x) + q1 * (kv0.y + t0.y) + q2 * (kv0.z + t0.z) + q3 * (kv0.w + t0.w);
            float s1 = q0 * (kv1.x + t1.x) + q1 * (kv1.y + t1.y) + q2 * (kv1.z + t1.z) + q3 * (kv1.w + t1.w);
            s0 += __shfl_xor(s0, 1, 64); s1 += __shfl_xor(s1, 1, 64);
            s0 += __shfl_xor(s0, 2, 64); s1 += __shfl_xor(s1, 2, 64);
            s0 += __shfl_xor(s0, 4, 64); s1 += __shfl_xor(s1, 4, 64);
            s0 += __shfl_xor(s0, 8, 64); s1 += __shfl_xor(s1, 8, 64);
            if ((lane & 15) == 0) {
                p[h][k0    ] = s0 * 0.125f;
                p[h][k0 + 4] = s1 * 0.125f;
            }
        }
        if (i < nact) {
            int k = w + 4 * i;
            float4 kv = *(const float4*)(Kb + k * 256);
            float4 t4 = *(const float4*)(tKb + stm[k] * 256);
            float s = q0 * (kv.x + t4.x) + q1 * (kv.y + t4.y) + q2 * (kv.z + t4.z) + q3 * (kv.w + t4.w);
            s += __shfl_xor(s, 1, 64);
            s += __shfl_xor(s, 2, 64);
            s += __shfl_xor(s, 4, 64);
            s += __shfl_xor(s, 8, 64);
            if ((lane & 15) == 0) p[h][k] = s * 0.125f;
        }
    }
    __syncthreads();

    // --- softmax: wave w owns head w; invalid k (> qpos) masked at read (p holds garbage there)
    {
        float* ph = &p[w][0];
        float v0 = (lane       <= qpos) ? ph[lane      ] : BIG_NEG_F;
        float v1 = (lane + 64  <= qpos) ? ph[lane + 64 ] : BIG_NEG_F;
        float v2 = (lane + 128 <= qpos) ? ph[lane + 128] : BIG_NEG_F;
        float v3 = (lane + 192 <= qpos) ? ph[lane + 192] : BIG_NEG_F;
        float mx = wave_max(fmaxf(fmaxf(v0, v1), fmaxf(v2, v3)));
        float e0 = __expf(v0 - mx), e1 = __expf(v1 - mx), e2 = __expf(v2 - mx), e3 = __expf(v3 - mx);
        ph[lane] = e0; ph[lane + 64] = e1; ph[lane + 128] = e2; ph[lane + 192] = e3;
        float ssum = wave_sum(e0 + e1 + e2 + e3);
        if (lane == 0) denom[w] = ssum;
    }
    __syncthreads();

    // --- phase 3: PV, batch-2 with independent accumulators
    {
        int hh = lane >> 4;                 // head of this lane's 4 dims
        const float* Vb  = Vp + (size_t)(b << 8) * 256 + lane * 4;
        const float* tVb = tV + lane * 4;
        const float* prow = &p[hh][0];
        float4 a0 = {0.f, 0.f, 0.f, 0.f}, a1 = a0;
        int cnt = (qpos >= w) ? ((qpos - w) >> 2) + 1 : 0;
        int i = 0;
        for (; i + 2 <= cnt; i += 2) {
            int k0 = w + 4 * i;
            float p0 = prow[k0], p1 = prow[k0 + 4];
            float4 v0 = *(const float4*)(Vb + (k0    ) * 256);
            float4 v1 = *(const float4*)(Vb + (k0 + 4) * 256);
            float4 u0 = *(const float4*)(tVb + stm[k0    ] * 256);
            float4 u1 = *(const float4*)(tVb + stm[k0 + 4] * 256);
            a0.x += p0 * (v0.x + u0.x); a0.y += p0 * (v0.y + u0.y); a0.z += p0 * (v0.z + u0.z); a0.w += p0 * (v0.w + u0.w);
            a1.x += p1 * (v1.x + u1.x); a1.y += p1 * (v1.y + u1.y); a1.z += p1 * (v1.z + u1.z); a1.w += p1 * (v1.w + u1.w);
        }
        if (i < cnt) {
            int k2 = w + 4 * i;
            float pk = prow[k2];
            float4 v = *(const float4*)(Vb + k2 * 256);
            float4 t = *(const float4*)(tVb + stm[k2] * 256);
            a0.x += pk * (v.x + t.x);
            a0.y += pk * (v.y + t.y);
            a0.z += pk * (v.z + t.z);
            a0.w += pk * (v.w + t.w);
        }
        float4 o;
        o.x = a0.x + a1.x;
        o.y = a0.y + a1.y;
        o.z = a0.z + a1.z;
        o.w = a0.w + a1.w;
        *(float4*)&opart[w][lane * 4] = o;
    }
    __syncthreads();

    // --- combine + fused ln2
    {
        int d = tid, h = tid >> 6;
        float tot = opart[0][d] + opart[1][d] + opart[2][d] + opart[3][d];
        float xv = qres[rowbase + d] + tot / denom[h];
        float s = wave_sum(xv);
        if (lane == 0) lnws[w] = s;
        __syncthreads();
        float mean = (lnws[0] + lnws[1] + lnws[2] + lnws[3]) * (1.f / 256.f);
        float dd = xv - mean;
        float s2 = wave_sum(dd * dd);
        if (lane == 0) lnws[4 + w] = s2;
        __syncthreads();
        float var = (lnws[4] + lnws[5] + lnws[6] + lnws[7]) * (1.f / 256.f);
        X2[rowbase + d] = dd / sqrtf(var + 1e-8f) * g2[d] + b2[d];
    }
}

extern "C" void kernel_launch(void* const* d_in, const int* in_sizes, int n_in,
                              void* d_out, int out_size, void* d_ws, size_t ws_size,
                              hipStream_t stream) {
    const unsigned char* mask_raw = (const unsigned char*)d_in[0];
    const float* seq  = (const float*)d_in[1];
    const int*   tm   = (const int*)d_in[3];
    const float* Wq   = (const float*)d_in[5];
    const float* bq   = (const float*)d_in[6];
    const float* Wk   = (const float*)d_in[7];
    const float* bk   = (const float*)d_in[8];
    const float* Wv   = (const float*)d_in[9];
    const float* bv   = (const float*)d_in[10];
    const float* ln1g = (const float*)d_in[11];
    const float* ln1b = (const float*)d_in[12];
    const float* ln2g = (const float*)d_in[13];
    const float* ln2b = (const float*)d_in[14];
    const float* W1   = (const float*)d_in[15];
    const float* b1   = (const float*)d_in[16];
    const float* W2   = (const float*)d_in[17];
    const float* b2   = (const float*)d_in[18];
    const float* posK = (const float*)d_in[19];
    const float* posV = (const float*)d_in[20];
    const float* tK   = (const float*)d_in[21];
    const float* tV   = (const float*)d_in[22];
    const float* lnfg = (const float*)d_in[23];
    const float* lnfb = (const float*)d_in[24];

    const int NEL = 8 * 256 * 256;
    float* x   = (float*)d_ws;
    float* q   = x   + NEL;
    float* Qb  = q   + NEL;
    float* KpB = Qb  + NEL;
    float* VpB = KpB + NEL;
    float* x2  = VpB + NEL;
    float* hb  = x2  + NEL;
    unsigned char* mask = (unsigned char*)(hb + NEL);

    dim3 gQKV(4, 32, 3);
    dim3 gFFN(8, 64);

    prep_ln_kernel<<<2048, 256, 0, stream>>>(seq, mask_raw, mask, x, q, ln1g, ln1b);
    for (int blk = 0; blk < 2; ++blk) {
        int o1 = blk * 256, oW = blk * 256 * 256;
        GemmJob jq = {q, Wq + oW, bq + o1, nullptr, Qb};
        GemmJob jk = {x, Wk + oW, bk + o1, posK,    KpB};
        GemmJob jv = {x, Wv + oW, bv + o1, posV,    VpB};
        gemm64_kernel<<<gQKV, 256, 0, stream>>>(jq, jk, jv);
        attn_kernel<<<2048, 256, 0, stream>>>(Qb, KpB, VpB, q, tm, tK, tV,
                                              ln2g + o1, ln2b + o1, x2);
        gemm32_kernel<<<gFFN, 256, 0, stream>>>(x2, W1 + oW, b1 + o1, nullptr, nullptr, hb, 1);
        gemm32_kernel<<<gFFN, 256, 0, stream>>>(hb, W2 + oW, b2 + o1, x2, mask, x, 0);
        if (blk == 0) ln_kernel<<<2048, 256, 0, stream>>>(x, q, ln1g + 256, ln1b + 256);
    }
    ln_kernel<<<2048, 256, 0, stream>>>(x, (float*)d_out, lnfg, lnfb);
}

// Round 11
// 255.394 us; speedup vs baseline: 1.3529x; 1.0656x over previous
//
#include <hip/hip_runtime.h>

#define BIG_NEG_F (-4294967296.0f)

typedef __attribute__((ext_vector_type(8))) short bf16x8;
typedef __attribute__((ext_vector_type(4))) float f32x4;

__device__ __forceinline__ float wave_sum(float v) {
#pragma unroll
    for (int m = 32; m; m >>= 1) v += __shfl_xor(v, m, 64);
    return v;
}
__device__ __forceinline__ float wave_max(float v) {
#pragma unroll
    for (int m = 32; m; m >>= 1) v = fmaxf(v, __shfl_xor(v, m, 64));
    return v;
}

__device__ __forceinline__ unsigned int pack2(float a, float b) {
    return (__float_as_uint(b) & 0xffff0000u) | (__float_as_uint(a) >> 16);
}
__device__ __forceinline__ float hipart(float x) {
    return __uint_as_float(__float_as_uint(x) & 0xffff0000u);
}
// split two float4 into hi/lo bf16 (truncation split: hi exact-representable, lo = residual)
__device__ __forceinline__ void store_pair(unsigned short* hp, unsigned short* lp,
                                           float4 a, float4 b) {
    uint4 h;
    h.x = pack2(a.x, a.y); h.y = pack2(a.z, a.w);
    h.z = pack2(b.x, b.y); h.w = pack2(b.z, b.w);
    float lax = a.x - hipart(a.x), lay = a.y - hipart(a.y);
    float laz = a.z - hipart(a.z), law = a.w - hipart(a.w);
    float lbx = b.x - hipart(b.x), lby = b.y - hipart(b.y);
    float lbz = b.z - hipart(b.z), lbw = b.w - hipart(b.w);
    uint4 l;
    l.x = pack2(lax, lay); l.y = pack2(laz, law);
    l.z = pack2(lbx, lby); l.w = pack2(lbz, lbw);
    *(uint4*)hp = h;
    *(uint4*)lp = l;
}

// Fused: detect mask layout (u8/i32/i64) from first 2048 bytes, normalize this row's bit,
// x = seq*keep, q = ln1(x). One block per row.
__global__ __launch_bounds__(256) void prep_ln_kernel(const float* __restrict__ seq,
                                                      const unsigned char* __restrict__ mraw,
                                                      unsigned char* __restrict__ mout,
                                                      float* __restrict__ X, float* __restrict__ Q,
                                                      const float* __restrict__ g,
                                                      const float* __restrict__ be) {
    __shared__ int flags[2];
    __shared__ float ws[8];
    int row = blockIdx.x, tid = threadIdx.x;
    if (tid == 0) { flags[0] = 0; flags[1] = 0; }
    __syncthreads();
    for (int i = tid; i < 2048; i += 256) {
        if (mraw[i]) {
            if (i & 3) atomicOr(&flags[0], 1);
            else if (i & 4) atomicOr(&flags[1], 1);
        }
    }
    __syncthreads();
    int mode = flags[0] ? 0 : (flags[1] ? 1 : 2);  // 0=u8, 1=i32, 2=i64
    unsigned char mrow = (mode == 0) ? mraw[row] : (mode == 1) ? mraw[row * 4] : mraw[row * 8];
    if (tid == 0) mout[row] = mrow ? 1 : 0;
    int idx = row * 256 + tid;
    int w = tid >> 6, lane = tid & 63;
    float v = mrow ? 0.f : seq[idx];
    X[idx] = v;
    float s = wave_sum(v);
    if (lane == 0) ws[w] = s;
    __syncthreads();
    float mean = (ws[0] + ws[1] + ws[2] + ws[3]) * (1.f / 256.f);
    float d = v - mean;
    float s2 = wave_sum(d * d);
    if (lane == 0) ws[4 + w] = s2;
    __syncthreads();
    float var = (ws[4] + ws[5] + ws[6] + ws[7]) * (1.f / 256.f);
    Q[idx] = d / sqrtf(var + 1e-8f) * g[tid] + be[tid];
}

// row layernorm over H=256, one block per row; shfl reductions (2 barriers)
__global__ __launch_bounds__(256) void ln_kernel(const float* __restrict__ X, float* __restrict__ Y,
                                                 const float* __restrict__ g,
                                                 const float* __restrict__ be) {
    __shared__ float ws[8];
    int row = blockIdx.x, tid = threadIdx.x;
    int idx = row * 256 + tid;
    int w = tid >> 6, lane = tid & 63;
    float v = X[idx];
    float s = wave_sum(v);
    if (lane == 0) ws[w] = s;
    __syncthreads();
    float mean = (ws[0] + ws[1] + ws[2] + ws[3]) * (1.f / 256.f);
    float d = v - mean;
    float s2 = wave_sum(d * d);
    if (lane == 0) ws[4 + w] = s2;
    __syncthreads();
    float var = (ws[4] + ws[5] + ws[6] + ws[7]) * (1.f / 256.f);
    Y[idx] = d / sqrtf(var + 1e-8f) * g[tid] + be[tid];
}

struct GemmJob {
    const float* A;            // [2048,256]
    const float* W;            // [256,256] row-major (out,in)
    const float* bias;         // [256]
    const float* pos;          // [256,256] per-position add, or null
    const float* res;          // residual add, or null
    const unsigned char* maskm;// row mask (zero out), or null
    float* C;                  // [2048,256]
    int relu;
};

// MFMA GEMM (retry — round 10 bench died to infra, no kernel signal): C = A·W^T via
// split-precision bf16 (hi/lo): A·B ≈ Ah·Bh + Ah·Bl + Al·Bh, rel err ~2^-16 (≈fp32).
// Escapes the 157TF fp32 vector ceiling (matrix pipe: 2.5PF).
// 64x64 tile, BK=64, 4 waves as 2x2 (each wave 32x32 = 4 frags of 16x16, K=32 MFMA).
// Fragment layouts: A: row=lane&15, k=(lane>>4)*8+j; B: col=lane&15, same k (both
// row-major [rows][K] in LDS — no transpose needed); C/D [m89-verified]: col=lane&15,
// row=(lane>>4)*4+r. LDS rows padded to 72 ushorts (144B = 9x16B: aligned b128 reads,
// even bank spread). Register-prefetch of next K-tile's fp32 under the MFMA compute.
__global__ __launch_bounds__(256) void gemm_mfma_kernel(GemmJob j0, GemmJob j1, GemmJob j2) {
    GemmJob J = (blockIdx.z == 0) ? j0 : (blockIdx.z == 1 ? j1 : j2);
    __shared__ unsigned short Ah[64][72], Al[64][72], Wh[64][72], Wl[64][72];
    int tid = threadIdx.x;
    int n0 = blockIdx.x * 64, m0 = blockIdx.y * 64;
    int w = tid >> 6, lane = tid & 63;
    int wm = w >> 1, wn = w & 1;
    int srow = tid >> 2, sq = tid & 3;          // staging: row 0..63, k-quarter 0..3
    const float* Asrc = J.A + (m0 + srow) * 256 + sq * 16;
    const float* Wsrc = J.W + (n0 + srow) * 256 + sq * 16;
    float4 ar0 = *(const float4*)(Asrc),      ar1 = *(const float4*)(Asrc + 4),
           ar2 = *(const float4*)(Asrc + 8),  ar3 = *(const float4*)(Asrc + 12);
    float4 wr0 = *(const float4*)(Wsrc),      wr1 = *(const float4*)(Wsrc + 4),
           wr2 = *(const float4*)(Wsrc + 8),  wr3 = *(const float4*)(Wsrc + 12);
    f32x4 acc[2][2] = {};
    int r15 = lane & 15, hgrp = (lane >> 4) << 3;
    for (int kt = 0; kt < 4; ++kt) {
        if (kt) __syncthreads();                // previous compute done before overwrite
        store_pair(&Ah[srow][sq * 16],     &Al[srow][sq * 16],     ar0, ar1);
        store_pair(&Ah[srow][sq * 16 + 8], &Al[srow][sq * 16 + 8], ar2, ar3);
        store_pair(&Wh[srow][sq * 16],     &Wl[srow][sq * 16],     wr0, wr1);
        store_pair(&Wh[srow][sq * 16 + 8], &Wl[srow][sq * 16 + 8], wr2, wr3);
        __syncthreads();
        if (kt < 3) {                           // prefetch next K-tile; retires under MFMAs
            int ko = (kt + 1) * 64;
            ar0 = *(const float4*)(Asrc + ko);      ar1 = *(const float4*)(Asrc + ko + 4);
            ar2 = *(const float4*)(Asrc + ko + 8);  ar3 = *(const float4*)(Asrc + ko + 12);
            wr0 = *(const float4*)(Wsrc + ko);      wr1 = *(const float4*)(Wsrc + ko + 4);
            wr2 = *(const float4*)(Wsrc + ko + 8);  wr3 = *(const float4*)(Wsrc + ko + 12);
        }
#pragma unroll
        for (int s = 0; s < 2; ++s) {
            int ko = s * 32 + hgrp;
            bf16x8 ah0 = *(const bf16x8*)&Ah[wm * 32 + r15][ko];
            bf16x8 ah1 = *(const bf16x8*)&Ah[wm * 32 + 16 + r15][ko];
            bf16x8 al0 = *(const bf16x8*)&Al[wm * 32 + r15][ko];
            bf16x8 al1 = *(const bf16x8*)&Al[wm * 32 + 16 + r15][ko];
            bf16x8 bh0 = *(const bf16x8*)&Wh[wn * 32 + r15][ko];
            bf16x8 bh1 = *(const bf16x8*)&Wh[wn * 32 + 16 + r15][ko];
            bf16x8 bl0 = *(const bf16x8*)&Wl[wn * 32 + r15][ko];
            bf16x8 bl1 = *(const bf16x8*)&Wl[wn * 32 + 16 + r15][ko];
            acc[0][0] = __builtin_amdgcn_mfma_f32_16x16x32_bf16(ah0, bh0, acc[0][0], 0, 0, 0);
            acc[0][0] = __builtin_amdgcn_mfma_f32_16x16x32_bf16(ah0, bl0, acc[0][0], 0, 0, 0);
            acc[0][0] = __builtin_amdgcn_mfma_f32_16x16x32_bf16(al0, bh0, acc[0][0], 0, 0, 0);
            acc[0][1] = __builtin_amdgcn_mfma_f32_16x16x32_bf16(ah0, bh1, acc[0][1], 0, 0, 0);
            acc[0][1] = __builtin_amdgcn_mfma_f32_16x16x32_bf16(ah0, bl1, acc[0][1], 0, 0, 0);
            acc[0][1] = __builtin_amdgcn_mfma_f32_16x16x32_bf16(al0, bh1, acc[0][1], 0, 0, 0);
            acc[1][0] = __builtin_amdgcn_mfma_f32_16x16x32_bf16(ah1, bh0, acc[1][0], 0, 0, 0);
            acc[1][0] = __builtin_amdgcn_mfma_f32_16x16x32_bf16(ah1, bl0, acc[1][0], 0, 0, 0);
            acc[1][0] = __builtin_amdgcn_mfma_f32_16x16x32_bf16(al1, bh0, acc[1][0], 0, 0, 0);
            acc[1][1] = __builtin_amdgcn_mfma_f32_16x16x32_bf16(ah1, bh1, acc[1][1], 0, 0, 0);
            acc[1][1] = __builtin_amdgcn_mfma_f32_16x16x32_bf16(ah1, bl1, acc[1][1], 0, 0, 0);
            acc[1][1] = __builtin_amdgcn_mfma_f32_16x16x32_bf16(al1, bh1, acc[1][1], 0, 0, 0);
        }
    }
    // epilogue: C/D layout col=lane&15, row=(lane>>4)*4+r
#pragma unroll
    for (int mf = 0; mf < 2; ++mf) {
#pragma unroll
        for (int nf = 0; nf < 2; ++nf) {
            int col = n0 + wn * 32 + nf * 16 + r15;
            int rowb = m0 + wm * 32 + mf * 16 + ((lane >> 4) << 2);
            float bcol = J.bias[col];
            f32x4 a = acc[mf][nf];
#pragma unroll
            for (int rr = 0; rr < 4; ++rr) {
                int m = rowb + rr;
                float v = a[rr] + bcol;
                if (J.pos) v += J.pos[(m & 255) * 256 + col];
                if (J.relu) v = fmaxf(v, 0.f);
                if (J.res) v += J.res[m * 256 + col];
                if (J.maskm && J.maskm[m]) v = 0.f;
                J.C[m * 256 + col] = v;
            }
        }
    }
}

// 2048 one-qpos blocks. b = bid&7 keeps XCD affinity (each XCD touches one batch's
// K/V/Q/qres/tm ~2.3MB -> fits 4MiB private L2; FETCH 51->9.3MB measured). qpos map is
// per-CU balanced: i=bid>>3, j=i&31, a=i>>5, q0=j*4+(a>>1), qpos=(a&1)?q0:255-q0 —
// bijective over [0,256); under round-robin (id%8->XCD, (id/8)%32->CU) each CU's 8
// blocks sum to exactly 1028 rows. Inner loops batch-2 (4 float4 in flight): fits the
// 64-VGPR budget of __launch_bounds__(256,8) with NO scratch traffic. Batch-4 spills —
// verified rounds 1/2/4/6 (WRITE_SIZE 7.9-22.5MB vs 2.0MB here). Do not raise depth.
__global__ __launch_bounds__(256, 8) void attn_kernel(
    const float* __restrict__ Q, const float* __restrict__ Kp, const float* __restrict__ Vp,
    const float* __restrict__ qres, const int* __restrict__ tm,
    const float* __restrict__ tK, const float* __restrict__ tV,
    const float* __restrict__ g2, const float* __restrict__ b2,
    float* __restrict__ X2) {
    int bid = (int)blockIdx.x;
    int b = bid & 7;                    // XCD-aligned batch
    int i6 = bid >> 3;                  // 0..255
    int jj6 = i6 & 31, a6 = i6 >> 5;
    int q0m = jj6 * 4 + (a6 >> 1);      // 0..127
    int qpos = (a6 & 1) ? q0m : 255 - q0m;
    int tid = threadIdx.x, w = tid >> 6, lane = tid & 63;
    __shared__ float qrow[256];
    __shared__ int   stm[256];
    __shared__ float p[4][264];     // 264: writer lanes spread banks
    __shared__ float opart[4][256];
    __shared__ float denom[4];
    __shared__ float lnws[8];

    int rowbase = (b * 256 + qpos) * 256;
    qrow[tid] = Q[rowbase + tid];
    {
        int t = tm[rowbase + tid];
        stm[tid] = t < 0 ? 0 : (t > 512 ? 512 : t);
    }
    __syncthreads();

    // --- phase 1: scores, k ≡ w (mod 4) per wave — balanced across waves; batch-2
    {
        int h = lane >> 4;
        const float* qr = qrow + lane * 4;
        float q0 = qr[0], q1 = qr[1], q2 = qr[2], q3 = qr[3];
        const float* Kb  = Kp + (size_t)(b << 8) * 256 + lane * 4;
        const float* tKb = tK + lane * 4;
        int nact = (qpos >= w) ? ((qpos - w) >> 2) + 1 : 0;  // #k in {w, w+4, ...} <= qpos
        int i = 0;
        for (; i + 2 <= nact; i += 2) {
            int k0 = w + 4 * i;          // rows k0, k0+4
            float4 kv0 = *(const float4*)(Kb + (k0    ) * 256);
            float4 kv1 = *(const float4*)(Kb + (k0 + 4) * 256);
            float4 t0 = *(const float4*)(tKb + stm[k0    ] * 256);
            float4 t1 = *(const float4*)(tKb + stm[k0 + 4] * 256);
            float s0 = q0 * (kv0.x + t0.x) + q1 * (kv0.y + t0.y) + q2 * (kv0.z + t0.z) + q3 * (kv0.w + t0.w);
            float s1 = q0 * (kv1.x + t1.x) + q1 * (kv1.y + t1.y) + q2 * (kv1.z + t1.z) + q3 * (kv1.w + t1.w);
            s0 += __shfl_xor(s0, 1, 64); s1 += __shfl_xor(s1, 1, 64);
            s0 += __shfl_xor(s0, 2, 64); s1 += __shfl_xor(s1, 2, 64);
            s0 += __shfl_xor(s0, 4, 64); s1 += __shfl_xor(s1, 4, 64);
            s0 += __shfl_xor(s0, 8, 64); s1 += __shfl_xor(s1, 8, 64);
            if ((lane & 15) == 0) {
                p[h][k0    ] = s0 * 0.125f;
                p[h][k0 + 4] = s1 * 0.125f;
            }
        }
        if (i < nact) {
            int k = w + 4 * i;
            float4 kv = *(const float4*)(Kb + k * 256);
            float4 t4 = *(const float4*)(tKb + stm[k] * 256);
            float s = q0 * (kv.x + t4.x) + q1 * (kv.y + t4.y) + q2 * (kv.z + t4.z) + q3 * (kv.w + t4.w);
            s += __shfl_xor(s, 1, 64);
            s += __shfl_xor(s, 2, 64);
            s += __shfl_xor(s, 4, 64);
            s += __shfl_xor(s, 8, 64);
            if ((lane & 15) == 0) p[h][k] = s * 0.125f;
        }
    }
    __syncthreads();

    // --- softmax: wave w owns head w; invalid k (> qpos) masked at read (p holds garbage there)
    {
        float* ph = &p[w][0];
        float v0 = (lane       <= qpos) ? ph[lane      ] : BIG_NEG_F;
        float v1 = (lane + 64  <= qpos) ? ph[lane + 64 ] : BIG_NEG_F;
        float v2 = (lane + 128 <= qpos) ? ph[lane + 128] : BIG_NEG_F;
        float v3 = (lane + 192 <= qpos) ? ph[lane + 192] : BIG_NEG_F;
        float mx = wave_max(fmaxf(fmaxf(v0, v1), fmaxf(v2, v3)));
        float e0 = __expf(v0 - mx), e1 = __expf(v1 - mx), e2 = __expf(v2 - mx), e3 = __expf(v3 - mx);
        ph[lane] = e0; ph[lane + 64] = e1; ph[lane + 128] = e2; ph[lane + 192] = e3;
        float ssum = wave_sum(e0 + e1 + e2 + e3);
        if (lane == 0) denom[w] = ssum;
    }
    __syncthreads();

    // --- phase 3: PV, batch-2 with independent accumulators
    {
        int hh = lane >> 4;                 // head of this lane's 4 dims
        const float* Vb  = Vp + (size_t)(b << 8) * 256 + lane * 4;
        const float* tVb = tV + lane * 4;
        const float* prow = &p[hh][0];
        float4 a0 = {0.f, 0.f, 0.f, 0.f}, a1 = a0;
        int cnt = (qpos >= w) ? ((qpos - w) >> 2) + 1 : 0;
        int i = 0;
        for (; i + 2 <= cnt; i += 2) {
            int k0 = w + 4 * i;
            float p0 = prow[k0], p1 = prow[k0 + 4];
            float4 v0 = *(const float4*)(Vb + (k0    ) * 256);
            float4 v1 = *(const float4*)(Vb + (k0 + 4) * 256);
            float4 u0 = *(const float4*)(tVb + stm[k0    ] * 256);
            float4 u1 = *(const float4*)(tVb + stm[k0 + 4] * 256);
            a0.x += p0 * (v0.x + u0.x); a0.y += p0 * (v0.y + u0.y); a0.z += p0 * (v0.z + u0.z); a0.w += p0 * (v0.w + u0.w);
            a1.x += p1 * (v1.x + u1.x); a1.y += p1 * (v1.y + u1.y); a1.z += p1 * (v1.z + u1.z); a1.w += p1 * (v1.w + u1.w);
        }
        if (i < cnt) {
            int k2 = w + 4 * i;
            float pk = prow[k2];
            float4 v = *(const float4*)(Vb + k2 * 256);
            float4 t = *(const float4*)(tVb + stm[k2] * 256);
            a0.x += pk * (v.x + t.x);
            a0.y += pk * (v.y + t.y);
            a0.z += pk * (v.z + t.z);
            a0.w += pk * (v.w + t.w);
        }
        float4 o;
        o.x = a0.x + a1.x;
        o.y = a0.y + a1.y;
        o.z = a0.z + a1.z;
        o.w = a0.w + a1.w;
        *(float4*)&opart[w][lane * 4] = o;
    }
    __syncthreads();

    // --- combine + fused ln2
    {
        int d = tid, h = tid >> 6;
        float tot = opart[0][d] + opart[1][d] + opart[2][d] + opart[3][d];
        float xv = qres[rowbase + d] + tot / denom[h];
        float s = wave_sum(xv);
        if (lane == 0) lnws[w] = s;
        __syncthreads();
        float mean = (lnws[0] + lnws[1] + lnws[2] + lnws[3]) * (1.f / 256.f);
        float dd = xv - mean;
        float s2 = wave_sum(dd * dd);
        if (lane == 0) lnws[4 + w] = s2;
        __syncthreads();
        float var = (lnws[4] + lnws[5] + lnws[6] + lnws[7]) * (1.f / 256.f);
        X2[rowbase + d] = dd / sqrtf(var + 1e-8f) * g2[d] + b2[d];
    }
}

extern "C" void kernel_launch(void* const* d_in, const int* in_sizes, int n_in,
                              void* d_out, int out_size, void* d_ws, size_t ws_size,
                              hipStream_t stream) {
    const unsigned char* mask_raw = (const unsigned char*)d_in[0];
    const float* seq  = (const float*)d_in[1];
    const int*   tm   = (const int*)d_in[3];
    const float* Wq   = (const float*)d_in[5];
    const float* bq   = (const float*)d_in[6];
    const float* Wk   = (const float*)d_in[7];
    const float* bk   = (const float*)d_in[8];
    const float* Wv   = (const float*)d_in[9];
    const float* bv   = (const float*)d_in[10];
    const float* ln1g = (const float*)d_in[11];
    const float* ln1b = (const float*)d_in[12];
    const float* ln2g = (const float*)d_in[13];
    const float* ln2b = (const float*)d_in[14];
    const float* W1   = (const float*)d_in[15];
    const float* b1   = (const float*)d_in[16];
    const float* W2   = (const float*)d_in[17];
    const float* b2   = (const float*)d_in[18];
    const float* posK = (const float*)d_in[19];
    const float* posV = (const float*)d_in[20];
    const float* tK   = (const float*)d_in[21];
    const float* tV   = (const float*)d_in[22];
    const float* lnfg = (const float*)d_in[23];
    const float* lnfb = (const float*)d_in[24];

    const int NEL = 8 * 256 * 256;
    float* x   = (float*)d_ws;
    float* q   = x   + NEL;
    float* Qb  = q   + NEL;
    float* KpB = Qb  + NEL;
    float* VpB = KpB + NEL;
    float* x2  = VpB + NEL;
    float* hb  = x2  + NEL;
    unsigned char* mask = (unsigned char*)(hb + NEL);

    dim3 gQKV(4, 32, 3);   // 384 blocks
    dim3 gFFN(4, 32, 1);   // 128 blocks

    prep_ln_kernel<<<2048, 256, 0, stream>>>(seq, mask_raw, mask, x, q, ln1g, ln1b);
    for (int blk = 0; blk < 2; ++blk) {
        int o1 = blk * 256, oW = blk * 256 * 256;
        GemmJob jq = {q, Wq + oW, bq + o1, nullptr, nullptr, nullptr, Qb, 0};
        GemmJob jk = {x, Wk + oW, bk + o1, posK,    nullptr, nullptr, KpB, 0};
        GemmJob jv = {x, Wv + oW, bv + o1, posV,    nullptr, nullptr, VpB, 0};
        gemm_mfma_kernel<<<gQKV, 256, 0, stream>>>(jq, jk, jv);
        attn_kernel<<<2048, 256, 0, stream>>>(Qb, KpB, VpB, q, tm, tK, tV,
                                              ln2g + o1, ln2b + o1, x2);
        GemmJob f1 = {x2, W1 + oW, b1 + o1, nullptr, nullptr, nullptr, hb, 1};
        gemm_mfma_kernel<<<gFFN, 256, 0, stream>>>(f1, f1, f1);
        GemmJob f2 = {hb, W2 + oW, b2 + o1, nullptr, x2, mask, x, 0};
        gemm_mfma_kernel<<<gFFN, 256, 0, stream>>>(f2, f2, f2);
        if (blk == 0) ln_kernel<<<2048, 256, 0, stream>>>(x, q, ln1g + 256, ln1b + 256);
    }
    ln_kernel<<<2048, 256, 0, stream>>>(x, (float*)d_out, lnfg, lnfb);
}